// Round 2
// baseline (204.787 us; speedup 1.0000x reference)
//
#include <hip/hip_runtime.h>
#include <hip/hip_bf16.h>

// SAGAN self-attention, MI355X (gfx950).
// B=4, N=4096 (64x64), C=128, d_qk=16. out = gamma * softmax(QK^T) V + x.
//
// Plan:
//  k1 qkv_proj : x[4,4096,128] f32 -> Qb,Kb [4,4096,16] bf16, Vt [4,128,4096] bf16 (V transposed)
//  k2 attn     : flash attention, mfma_f32_32x32x16_bf16 everywhere.
//                swapped QK^T (A=K, B=Q) -> lane owns one q-row's scores -> in-register softmax.
//                P->bf16 via packed pairs + v_permlane32_swap_b32 => PV A-fragment, no LDS round-trip.
//                k-split=2 across blocks; partial O for ks=0 stored in d_out (scratch reuse), ks=1 in ws.
//  k3 combine  : merge the two partials with (m,l) weights, * gamma + x -> d_out.

typedef __attribute__((ext_vector_type(8)))  short short8;
typedef __attribute__((ext_vector_type(16))) float f32x16;
typedef unsigned short u16;

#define LOG2E 1.4426950408889634f

__device__ __forceinline__ u16 f2bf(float f) {
  __hip_bfloat16 h = __float2bfloat16(f);
  return __builtin_bit_cast(u16, h);
}
__device__ __forceinline__ unsigned pk2bf(float lo, float hi) {
  return (unsigned)f2bf(lo) | ((unsigned)f2bf(hi) << 16);
}

// ---------------------------------------------------------------- kernel 1
__global__ __launch_bounds__(256) void qkv_proj(
    const float* __restrict__ x,
    const float* __restrict__ wq, const float* __restrict__ bq,
    const float* __restrict__ wk, const float* __restrict__ bk,
    const float* __restrict__ wv, const float* __restrict__ bv,
    u16* __restrict__ Qb, u16* __restrict__ Kb, u16* __restrict__ Vt)
{
  __shared__ float xs[64 * 132];          // 64 rows x 128, stride 132 (bank-spread)
  const int tid = threadIdx.x;
  const int b   = blockIdx.x >> 6;
  const int n0  = (blockIdx.x & 63) * 64;

  const float4* xg = (const float4*)(x + ((size_t)b * 4096 + n0) * 128);
#pragma unroll
  for (int p = 0; p < 8; ++p) {
    int idx = tid + p * 256;              // contiguous float4s: coalesced
    int n = idx >> 5, i4 = idx & 31;
    float4 v = xg[idx];
    *(float4*)(xs + n * 132 + i4 * 4) = v;
  }
  __syncthreads();

  const int n = tid >> 2;                 // 0..63 row
  const int g = tid & 3;                  // 0..3
  const float* xrow = xs + n * 132;

  // ---- V phase: this thread computes channels [g*32, g*32+32) of row n
  float acc[32];
#pragma unroll
  for (int cc = 0; cc < 32; ++cc) acc[cc] = 0.f;
  const float4* wv4 = (const float4*)wv + g * 8;
  for (int i = 0; i < 128; ++i) {
    float xv = xrow[i];
#pragma unroll
    for (int j = 0; j < 8; ++j) {
      float4 w = wv4[(size_t)i * 32 + j];
      acc[j*4+0] = fmaf(xv, w.x, acc[j*4+0]);
      acc[j*4+1] = fmaf(xv, w.y, acc[j*4+1]);
      acc[j*4+2] = fmaf(xv, w.z, acc[j*4+2]);
      acc[j*4+3] = fmaf(xv, w.w, acc[j*4+3]);
    }
  }
  {
    // transposed store: Vt[b][c][n0+n]; lanes n-consecutive -> coalesced rows
    size_t vbase = ((size_t)b * 128 + g * 32) * 4096 + (size_t)(n0 + n);
#pragma unroll
    for (int cc = 0; cc < 32; ++cc)
      Vt[vbase + (size_t)cc * 4096] = f2bf(acc[cc] + bv[g * 32 + cc]);
  }

  // ---- Q/K phase: g: 0 -> q[0:8], 1 -> q[8:16], 2 -> k[0:8], 3 -> k[8:16]
  const float* wm = (g & 2) ? wk : wq;
  const float* bm = (g & 2) ? bk : bq;
  const int off = (g & 1) * 8;
  float a8[8];
#pragma unroll
  for (int d = 0; d < 8; ++d) a8[d] = 0.f;
  const float4* wm4 = (const float4*)wm + (off >> 2);
  for (int i = 0; i < 128; ++i) {
    float xv = xrow[i];
    float4 w0 = wm4[i * 4 + 0];
    float4 w1 = wm4[i * 4 + 1];
    a8[0] = fmaf(xv, w0.x, a8[0]);  a8[1] = fmaf(xv, w0.y, a8[1]);
    a8[2] = fmaf(xv, w0.z, a8[2]);  a8[3] = fmaf(xv, w0.w, a8[3]);
    a8[4] = fmaf(xv, w1.x, a8[4]);  a8[5] = fmaf(xv, w1.y, a8[5]);
    a8[6] = fmaf(xv, w1.z, a8[6]);  a8[7] = fmaf(xv, w1.w, a8[7]);
  }
  short8 o;
#pragma unroll
  for (int d = 0; d < 8; ++d) o[d] = (short)f2bf(a8[d] + bm[off + d]);
  u16* dst = ((g & 2) ? Kb : Qb) + ((size_t)b * 4096 + n0 + n) * 16 + off;
  *(short8*)dst = o;                      // 16B aligned (off in {0,8})
}

// ---------------------------------------------------------------- kernel 2
// grid 256 = b(4) x qt(32) x ks(2). block 256 = 4 waves, wave owns 32 q-rows.
// Each block: q rows [qt*128, +128), k range [ks*2048, +2048), CK=64 chunks.
__global__ __launch_bounds__(256) void attn(
    const u16* __restrict__ Qb, const u16* __restrict__ Kb,
    const u16* __restrict__ Vt,
    float* __restrict__ O0, float* __restrict__ O1, float2* __restrict__ ML)
{
  // per buffer: V 128 rows x 144B (64 k bf16 + 16B pad) = 18432, K 64 rows x 48B = 3072
  __shared__ __align__(16) char sm[2][21504];
  const int tid  = threadIdx.x;
  const int lane = tid & 63;
  const int wid  = tid >> 6;
  const int ln31 = lane & 31;
  const int hi   = lane >> 5;

  const int b   = blockIdx.x >> 6;
  const int qt  = (blockIdx.x >> 1) & 31;
  const int ks  = blockIdx.x & 1;
  const int qw  = qt * 128 + wid * 32;    // wave's first q row (within batch)
  const int kb0 = ks * 2048;

  // Q B-fragment: col q = ln31, d = hi*8 + j  (contiguous 16B of Qb row)
  const short8 qf = *(const short8*)(Qb + (((size_t)b * 4096 + qw + ln31) << 4) + (hi << 3));

  f32x16 acc[4];
#pragma unroll
  for (int ct = 0; ct < 4; ++ct) acc[ct] = (f32x16)0.0f;
  float m = -1e30f, l = 0.f;

  const char* vg = (const char*)(Vt + (size_t)b * 128 * 4096);
  const char* kg = (const char*)(Kb + (size_t)b * 4096 * 16);
  const int vc = tid >> 1;                // V channel row this thread stages
  const int vp = tid & 1;                 // which 64B half of the 128B row

  uint4 rv0, rv1, rv2, rv3, rk;

  auto loadChunk = [&](int kb) {          // global -> regs (issued early, T14)
    const char* vs = vg + (size_t)vc * 8192 + (size_t)kb * 2 + vp * 64;
    rv0 = *(const uint4*)(vs);
    rv1 = *(const uint4*)(vs + 16);
    rv2 = *(const uint4*)(vs + 32);
    rv3 = *(const uint4*)(vs + 48);
    if (tid < 128)
      rk = *(const uint4*)(kg + (size_t)(kb + (tid >> 1)) * 32 + (tid & 1) * 16);
  };
  auto storeChunk = [&](char* buf) {      // regs -> LDS (after compute)
    char* vd = buf + vc * 144 + vp * 64;
    *(uint4*)(vd)      = rv0;
    *(uint4*)(vd + 16) = rv1;
    *(uint4*)(vd + 32) = rv2;
    *(uint4*)(vd + 48) = rv3;
    if (tid < 128)
      *(uint4*)(buf + 18432 + (tid >> 1) * 48 + (tid & 1) * 16) = rk;
  };

  auto compute = [&](const char* buf) {
    const char* kbuf = buf + 18432;
#pragma unroll
    for (int kt = 0; kt < 2; ++kt) {      // two 32-k subtiles per 64-k chunk
      // swapped QK^T: A = K rows (kk = ln31), B = Q -> D[kk][q], lane col = q
      short8 kf = *(const short8*)(kbuf + (kt * 32 + ln31) * 48 + hi * 16);
      f32x16 s = __builtin_amdgcn_mfma_f32_32x32x16_bf16(kf, qf, (f32x16)0.0f, 0, 0, 0);

      // online softmax for this lane's q-row: s[r] is kk = (r&3)+8*(r>>2)+4*hi
      float pmax = s[0];
#pragma unroll
      for (int r = 1; r < 16; ++r) pmax = fmaxf(pmax, s[r]);
      pmax = fmaxf(pmax, __shfl_xor(pmax, 32));
      if (__any(pmax > m + 8.0f)) {       // defer-max (T13), wave-uniform branch
        float mn = fmaxf(m, pmax);
        float al = exp2f((m - mn) * LOG2E);
        l *= al;
        m  = mn;
#pragma unroll
        for (int r = 0; r < 16; ++r) {
          float ar = __shfl(al, (r & 3) + 8 * (r >> 2) + 4 * hi); // alpha of acc-row q
          acc[0][r] *= ar; acc[1][r] *= ar; acc[2][r] *= ar; acc[3][r] *= ar;
        }
      }
      float p[16];
      float rs = 0.f;
#pragma unroll
      for (int r = 0; r < 16; ++r) { p[r] = exp2f((s[r] - m) * LOG2E); rs += p[r]; }
      rs += __shfl_xor(rs, 32);
      l += rs;

      // P -> bf16 PV A-fragments: packed pairs + permlane32_swap (T12)
      unsigned u0 = pk2bf(p[0], p[1]),  u1 = pk2bf(p[2], p[3]);
      unsigned u2 = pk2bf(p[4], p[5]),  u3 = pk2bf(p[6], p[7]);
      asm("v_permlane32_swap_b32 %0, %1" : "+v"(u0), "+v"(u2));
      asm("v_permlane32_swap_b32 %0, %1" : "+v"(u1), "+v"(u3));
      unsigned y0 = pk2bf(p[8], p[9]),   y1 = pk2bf(p[10], p[11]);
      unsigned y2 = pk2bf(p[12], p[13]), y3 = pk2bf(p[14], p[15]);
      asm("v_permlane32_swap_b32 %0, %1" : "+v"(y0), "+v"(y2));
      asm("v_permlane32_swap_b32 %0, %1" : "+v"(y1), "+v"(y3));
      union { unsigned u[4]; short8 s8; } pa0, pa1;
      pa0.u[0] = u0; pa0.u[1] = u1; pa0.u[2] = u2; pa0.u[3] = u3;
      pa1.u[0] = y0; pa1.u[1] = y1; pa1.u[2] = y2; pa1.u[3] = y3;

      // PV: acc[ct] += P[32q x 16k] @ V[16k x 32c], V B-frag = contiguous b128 of Vt row
#pragma unroll
      for (int ct = 0; ct < 4; ++ct) {
        const char* vrow = buf + (ct * 32 + ln31) * 144 + kt * 64 + hi * 16;
        short8 vf0 = *(const short8*)(vrow);        // k 0..15 of subtile
        short8 vf1 = *(const short8*)(vrow + 32);   // k 16..31
        acc[ct] = __builtin_amdgcn_mfma_f32_32x32x16_bf16(pa0.s8, vf0, acc[ct], 0, 0, 0);
        acc[ct] = __builtin_amdgcn_mfma_f32_32x32x16_bf16(pa1.s8, vf1, acc[ct], 0, 0, 0);
      }
    }
  };

  loadChunk(kb0);
  storeChunk(sm[0]);
  __syncthreads();
#pragma unroll 1
  for (int it = 0; it < 32; ++it) {
    if (it < 31) loadChunk(kb0 + (it + 1) * 64);  // HBM latency hides under compute
    compute(sm[it & 1]);
    if (it < 31) storeChunk(sm[(it + 1) & 1]);
    __syncthreads();                               // single barrier per iter (dbuf)
  }

  // epilogue: store partial (un-normalized) O and (m, l)
  if (lane < 32)
    ML[(size_t)ks * 16384 + (size_t)b * 4096 + qw + lane] = make_float2(m, l);
  float* Op = (ks ? O1 : O0) + ((size_t)b * 4096 + qw) * 128;
#pragma unroll
  for (int ct = 0; ct < 4; ++ct) {
#pragma unroll
    for (int r = 0; r < 16; ++r) {
      int q = (r & 3) + 8 * (r >> 2) + 4 * hi;     // C/D row map (m74/m101)
      Op[(size_t)q * 128 + ct * 32 + ln31] = acc[ct][r];
    }
  }
}

// ---------------------------------------------------------------- kernel 3
__global__ __launch_bounds__(256) void combine(
    const float* __restrict__ O1, const float2* __restrict__ ML,
    const float* __restrict__ x, const float* __restrict__ gamma,
    float* __restrict__ out)   // out currently holds the ks=0 partial
{
  int i    = blockIdx.x * 256 + threadIdx.x;   // 0..262143
  int nrow = i >> 4;
  int c0   = (i & 15) << 3;
  float2 ml0 = ML[nrow];
  float2 ml1 = ML[16384 + nrow];
  float M  = fmaxf(ml0.x, ml1.x);
  float w0 = exp2f((ml0.x - M) * LOG2E);
  float w1 = exp2f((ml1.x - M) * LOG2E);
  float inv = gamma[0] / fmaf(w0, ml0.y, w1 * ml1.y);
  size_t off = (size_t)nrow * 128 + c0;
  float4 p0a = *(const float4*)(out + off);
  float4 p0b = *(const float4*)(out + off + 4);
  float4 p1a = *(const float4*)(O1 + off);
  float4 p1b = *(const float4*)(O1 + off + 4);
  float4 xa  = *(const float4*)(x + off);
  float4 xb  = *(const float4*)(x + off + 4);
  float4 ra, rb;
  ra.x = fmaf(fmaf(w0, p0a.x, w1 * p1a.x), inv, xa.x);
  ra.y = fmaf(fmaf(w0, p0a.y, w1 * p1a.y), inv, xa.y);
  ra.z = fmaf(fmaf(w0, p0a.z, w1 * p1a.z), inv, xa.z);
  ra.w = fmaf(fmaf(w0, p0a.w, w1 * p1a.w), inv, xa.w);
  rb.x = fmaf(fmaf(w0, p0b.x, w1 * p1b.x), inv, xb.x);
  rb.y = fmaf(fmaf(w0, p0b.y, w1 * p1b.y), inv, xb.y);
  rb.z = fmaf(fmaf(w0, p0b.z, w1 * p1b.z), inv, xb.z);
  rb.w = fmaf(fmaf(w0, p0b.w, w1 * p1b.w), inv, xb.w);
  *(float4*)(out + off)     = ra;
  *(float4*)(out + off + 4) = rb;
}

// ---------------------------------------------------------------- launch
extern "C" void kernel_launch(void* const* d_in, const int* in_sizes, int n_in,
                              void* d_out, int out_size, void* d_ws, size_t ws_size,
                              hipStream_t stream)
{
  const float* x  = (const float*)d_in[0];
  const float* wq = (const float*)d_in[1];
  const float* bq = (const float*)d_in[2];
  const float* wk = (const float*)d_in[3];
  const float* bk = (const float*)d_in[4];
  const float* wv = (const float*)d_in[5];
  const float* bv = (const float*)d_in[6];
  const float* gm = (const float*)d_in[7];

  // ws layout (needs ~13.3 MB):
  //  [0, 512K)   Qb bf16 [4][4096][16]
  //  [512K, 1M)  Kb bf16 [4][4096][16]
  //  [1M, 5M)    Vt bf16 [4][128][4096]
  //  [5M, 13M)   O1 f32  [4][4096][128]   (ks=1 partial; ks=0 partial lives in d_out)
  //  [13M, +256K) ML f32x2 [2][4][4096]
  char* w = (char*)d_ws;
  u16*    Qb = (u16*)(w);
  u16*    Kb = (u16*)(w + (512ll << 10));
  u16*    Vt = (u16*)(w + (1ll << 20));
  float*  O1 = (float*)(w + (5ll << 20));
  float2* MLp = (float2*)(w + (13ll << 20));
  float*  out = (float*)d_out;

  qkv_proj<<<256, 256, 0, stream>>>(x, wq, bq, wk, bk, wv, bv, Qb, Kb, Vt);
  attn<<<256, 256, 0, stream>>>(Qb, Kb, Vt, out, O1, MLp);
  combine<<<1024, 256, 0, stream>>>(O1, MLp, x, gm, out);
}

// Round 3
// 84.514 us; speedup vs baseline: 2.4231x; 2.4231x over previous
//
#include <hip/hip_runtime.h>
#include <hip/hip_bf16.h>

// SAGAN self-attention, MI355X (gfx950).
// B=4, N=4096 (64x64), C=128, d_qk=16. out = gamma * softmax(QK^T) V + x.
//
//  k1 qkv_proj : MFMA GEMM x[16384,128] @ [wq|wk|wv] -> Qb,Kb bf16 [4,4096,16],
//                Vt bf16 [4,128,4096] (transposed). Q pre-scaled by log2(e).
//  k2 attn     : flash attention, mfma_f32_32x32x16_bf16, swapped QK^T,
//                in-register softmax (exp2-direct), P->bf16 + permlane32_swap,
//                k-split=2; ks=0 partial in d_out, ks=1 in ws.
//  k3 combine  : merge partials with (m,l), * gamma + x -> d_out.

typedef __attribute__((ext_vector_type(4)))  short short4v;
typedef __attribute__((ext_vector_type(8)))  short short8;
typedef __attribute__((ext_vector_type(16))) float f32x16;
typedef unsigned short u16;

#define LOG2E 1.4426950408889634f

__device__ __forceinline__ u16 f2bf(float f) {
  __hip_bfloat16 h = __float2bfloat16(f);
  return __builtin_bit_cast(u16, h);
}
__device__ __forceinline__ unsigned pk2bf(float lo, float hi) {
  return (unsigned)f2bf(lo) | ((unsigned)f2bf(hi) << 16);
}

// ---------------------------------------------------------------- kernel 1
// grid 128 = b(4) x rt(32): block computes rows [rt*128, +128) of batch b.
// LDS: xs bf16 [128][136], ws bf16 [160][136] (w^T: ws[outcol][k]).
// 20 MFMA tiles (mt 0..3 x nt 0..4), wave w owns tiles {w, w+4, ..., w+16}.
__global__ __launch_bounds__(256) void qkv_proj(
    const float* __restrict__ x,
    const float* __restrict__ wq, const float* __restrict__ bq,
    const float* __restrict__ wk, const float* __restrict__ bk,
    const float* __restrict__ wv, const float* __restrict__ bv,
    u16* __restrict__ Qb, u16* __restrict__ Kb, u16* __restrict__ Vt)
{
  __shared__ u16 xs[128 * 136];
  __shared__ u16 ws[160 * 136];
  const int tid = threadIdx.x;
  const int b   = blockIdx.x >> 5;
  const int n0  = (blockIdx.x & 31) * 128;

  // ---- stage x tile (f32 -> bf16), coalesced float4 loads
  const float4* xg = (const float4*)(x + ((size_t)b * 4096 + n0) * 128);
#pragma unroll
  for (int p = 0; p < 16; ++p) {
    int idx = tid + p * 256;              // 4096 float4s
    float4 v = xg[idx];
    int n = idx >> 5, i4 = idx & 31;
    short4v pk;
    pk[0] = (short)f2bf(v.x); pk[1] = (short)f2bf(v.y);
    pk[2] = (short)f2bf(v.z); pk[3] = (short)f2bf(v.w);
    *(short4v*)(xs + n * 136 + i4 * 4) = pk;
  }
  // ---- stage weights transposed: ws[col][k]; Q weights folded * LOG2E
#pragma unroll
  for (int p = 0; p < 8; ++p) {
    int idx = tid + p * 256;              // 2048 = 128x16
    int k = idx >> 4, d = idx & 15;
    ws[d * 136 + k]        = f2bf(wq[idx] * LOG2E);
    ws[(16 + d) * 136 + k] = f2bf(wk[idx]);
  }
#pragma unroll
  for (int p = 0; p < 64; ++p) {
    int idx = tid + p * 256;              // 16384 = 128x128
    int k = idx >> 7, c = idx & 127;
    ws[(32 + c) * 136 + k] = f2bf(wv[idx]);
  }
  __syncthreads();

  const int lane = tid & 63, wid = tid >> 6;
  const int ln31 = lane & 31, hi = lane >> 5;

#pragma unroll
  for (int j = 0; j < 5; ++j) {
    int t  = wid + j * 4;                 // 0..19
    int mt = t / 5, nt = t % 5;
    const u16* arow = xs + (mt * 32 + ln31) * 136 + hi * 8;
    const u16* brow = ws + (nt * 32 + ln31) * 136 + hi * 8;
    f32x16 acc = (f32x16)0.0f;
#pragma unroll
    for (int ks = 0; ks < 8; ++ks) {
      short8 a = *(const short8*)(arow + ks * 16);
      short8 w = *(const short8*)(brow + ks * 16);
      acc = __builtin_amdgcn_mfma_f32_32x32x16_bf16(a, w, acc, 0, 0, 0);
    }
    if (nt == 0) {
      // cols 0..15 -> Q (scaled), 16..31 -> K
      float bias = (ln31 < 16) ? bq[ln31] * LOG2E : bk[ln31 & 15];
      u16* base = ((ln31 < 16) ? Qb : Kb)
                + ((size_t)b * 4096 + n0 + mt * 32) * 16 + (ln31 & 15);
#pragma unroll
      for (int r = 0; r < 16; ++r) {
        int nl = (r & 3) + 8 * (r >> 2) + 4 * hi;   // C/D row map
        base[nl * 16] = f2bf(acc[r] + bias);
      }
    } else {
      int c = (nt - 1) * 32 + ln31;
      float bias = bv[c];
      u16* vb = Vt + ((size_t)b * 128 + c) * 4096 + n0 + mt * 32 + 4 * hi;
#pragma unroll
      for (int g = 0; g < 4; ++g) {       // rows g*8 + 4*hi + 0..3
        short4v pk;
        pk[0] = (short)f2bf(acc[g*4+0] + bias);
        pk[1] = (short)f2bf(acc[g*4+1] + bias);
        pk[2] = (short)f2bf(acc[g*4+2] + bias);
        pk[3] = (short)f2bf(acc[g*4+3] + bias);
        *(short4v*)(vb + 8 * g) = pk;
      }
    }
  }
}

// ---------------------------------------------------------------- kernel 2
// grid 256 = b(4) x qt(32) x ks(2). block 256 = 4 waves, wave owns 32 q-rows.
__global__ __launch_bounds__(256) void attn(
    const u16* __restrict__ Qb, const u16* __restrict__ Kb,
    const u16* __restrict__ Vt,
    float* __restrict__ O0, float* __restrict__ O1, float2* __restrict__ ML)
{
  // per buffer: V 128 rows x 144B (64 k bf16 + 16B pad) = 18432, K 64 rows x 48B = 3072
  __shared__ __align__(16) char sm[2][21504];
  const int tid  = threadIdx.x;
  const int lane = tid & 63;
  const int wid  = tid >> 6;
  const int ln31 = lane & 31;
  const int hi   = lane >> 5;

  const int b   = blockIdx.x >> 6;
  const int qt  = (blockIdx.x >> 1) & 31;
  const int ks  = blockIdx.x & 1;
  const int qw  = qt * 128 + wid * 32;    // wave's first q row (within batch)
  const int kb0 = ks * 2048;

  // Q B-fragment: col q = ln31, d = hi*8 + j (Q pre-scaled by log2e)
  const short8 qf = *(const short8*)(Qb + (((size_t)b * 4096 + qw + ln31) << 4) + (hi << 3));

  f32x16 acc[4];
#pragma unroll
  for (int ct = 0; ct < 4; ++ct) acc[ct] = (f32x16)0.0f;
  float m = -1e30f, l = 0.f;

  const char* vg = (const char*)(Vt + (size_t)b * 128 * 4096);
  const char* kg = (const char*)(Kb + (size_t)b * 4096 * 16);
  const int vc = tid >> 1;                // V channel row this thread stages
  const int vp = tid & 1;                 // which 64B half of the 128B row

  uint4 rv0, rv1, rv2, rv3, rk;

  auto loadChunk = [&](int kb) {          // global -> regs (issued early, T14)
    const char* vs = vg + (size_t)vc * 8192 + (size_t)kb * 2 + vp * 64;
    rv0 = *(const uint4*)(vs);
    rv1 = *(const uint4*)(vs + 16);
    rv2 = *(const uint4*)(vs + 32);
    rv3 = *(const uint4*)(vs + 48);
    if (tid < 128)
      rk = *(const uint4*)(kg + (size_t)(kb + (tid >> 1)) * 32 + (tid & 1) * 16);
  };
  auto storeChunk = [&](char* buf) {      // regs -> LDS (after compute)
    char* vd = buf + vc * 144 + vp * 64;
    *(uint4*)(vd)      = rv0;
    *(uint4*)(vd + 16) = rv1;
    *(uint4*)(vd + 32) = rv2;
    *(uint4*)(vd + 48) = rv3;
    if (tid < 128)
      *(uint4*)(buf + 18432 + (tid >> 1) * 48 + (tid & 1) * 16) = rk;
  };

  auto compute = [&](const char* buf) {
    const char* kbuf = buf + 18432;
#pragma unroll
    for (int kt = 0; kt < 2; ++kt) {      // two 32-k subtiles per 64-k chunk
      // swapped QK^T: A = K rows (kk = ln31), B = Q -> D[kk][q], lane col = q
      short8 kf = *(const short8*)(kbuf + (kt * 32 + ln31) * 48 + hi * 16);
      f32x16 s = __builtin_amdgcn_mfma_f32_32x32x16_bf16(kf, qf, (f32x16)0.0f, 0, 0, 0);

      // online softmax in log2 space: s[r] is kk = (r&3)+8*(r>>2)+4*hi
      float pmax = s[0];
#pragma unroll
      for (int r = 1; r < 16; ++r) pmax = fmaxf(pmax, s[r]);
      pmax = fmaxf(pmax, __shfl_xor(pmax, 32));
      if (__any(pmax > m + 8.0f)) {       // defer-max (T13), wave-uniform branch
        float mn = fmaxf(m, pmax);
        float al = exp2f(m - mn);
        l *= al;
        m  = mn;
#pragma unroll
        for (int r = 0; r < 16; ++r) {
          float ar = __shfl(al, (r & 3) + 8 * (r >> 2) + 4 * hi); // alpha of acc-row q
          acc[0][r] *= ar; acc[1][r] *= ar; acc[2][r] *= ar; acc[3][r] *= ar;
        }
      }
      float p[16];
      float rs = 0.f;
#pragma unroll
      for (int r = 0; r < 16; ++r) { p[r] = exp2f(s[r] - m); rs += p[r]; }
      rs += __shfl_xor(rs, 32);
      l += rs;

      // P -> bf16 PV A-fragments: packed pairs + permlane32_swap (T12)
      unsigned u0 = pk2bf(p[0], p[1]),  u1 = pk2bf(p[2], p[3]);
      unsigned u2 = pk2bf(p[4], p[5]),  u3 = pk2bf(p[6], p[7]);
      asm("v_permlane32_swap_b32 %0, %1" : "+v"(u0), "+v"(u2));
      asm("v_permlane32_swap_b32 %0, %1" : "+v"(u1), "+v"(u3));
      unsigned y0 = pk2bf(p[8], p[9]),   y1 = pk2bf(p[10], p[11]);
      unsigned y2 = pk2bf(p[12], p[13]), y3 = pk2bf(p[14], p[15]);
      asm("v_permlane32_swap_b32 %0, %1" : "+v"(y0), "+v"(y2));
      asm("v_permlane32_swap_b32 %0, %1" : "+v"(y1), "+v"(y3));
      union { unsigned u[4]; short8 s8; } pa0, pa1;
      pa0.u[0] = u0; pa0.u[1] = u1; pa0.u[2] = u2; pa0.u[3] = u3;
      pa1.u[0] = y0; pa1.u[1] = y1; pa1.u[2] = y2; pa1.u[3] = y3;

      // PV: acc[ct] += P[32q x 16k] @ V[16k x 32c], V B-frag = contiguous b128 of Vt row
#pragma unroll
      for (int ct = 0; ct < 4; ++ct) {
        const char* vrow = buf + (ct * 32 + ln31) * 144 + kt * 64 + hi * 16;
        short8 vf0 = *(const short8*)(vrow);        // k 0..15 of subtile
        short8 vf1 = *(const short8*)(vrow + 32);   // k 16..31
        acc[ct] = __builtin_amdgcn_mfma_f32_32x32x16_bf16(pa0.s8, vf0, acc[ct], 0, 0, 0);
        acc[ct] = __builtin_amdgcn_mfma_f32_32x32x16_bf16(pa1.s8, vf1, acc[ct], 0, 0, 0);
      }
    }
  };

  loadChunk(kb0);
  storeChunk(sm[0]);
  __syncthreads();
#pragma unroll 1
  for (int it = 0; it < 32; ++it) {
    if (it < 31) loadChunk(kb0 + (it + 1) * 64);  // HBM latency hides under compute
    compute(sm[it & 1]);
    if (it < 31) storeChunk(sm[(it + 1) & 1]);
    __syncthreads();                               // single barrier per iter (dbuf)
  }

  // epilogue: store partial (un-normalized) O and (m, l)
  if (lane < 32)
    ML[(size_t)ks * 16384 + (size_t)b * 4096 + qw + lane] = make_float2(m, l);
  float* Op = (ks ? O1 : O0) + ((size_t)b * 4096 + qw) * 128;
#pragma unroll
  for (int ct = 0; ct < 4; ++ct) {
#pragma unroll
    for (int r = 0; r < 16; ++r) {
      int q = (r & 3) + 8 * (r >> 2) + 4 * hi;     // C/D row map (m74/m101)
      Op[(size_t)q * 128 + ct * 32 + ln31] = acc[ct][r];
    }
  }
}

// ---------------------------------------------------------------- kernel 3
__global__ __launch_bounds__(256) void combine(
    const float* __restrict__ O1, const float2* __restrict__ ML,
    const float* __restrict__ x, const float* __restrict__ gamma,
    float* __restrict__ out)   // out currently holds the ks=0 partial
{
  int i    = blockIdx.x * 256 + threadIdx.x;   // 0..262143
  int nrow = i >> 4;
  int c0   = (i & 15) << 3;
  float2 ml0 = ML[nrow];
  float2 ml1 = ML[16384 + nrow];
  float M  = fmaxf(ml0.x, ml1.x);
  float w0 = exp2f(ml0.x - M);
  float w1 = exp2f(ml1.x - M);
  float inv = gamma[0] / fmaf(w0, ml0.y, w1 * ml1.y);
  size_t off = (size_t)nrow * 128 + c0;
  float4 p0a = *(const float4*)(out + off);
  float4 p0b = *(const float4*)(out + off + 4);
  float4 p1a = *(const float4*)(O1 + off);
  float4 p1b = *(const float4*)(O1 + off + 4);
  float4 xa  = *(const float4*)(x + off);
  float4 xb  = *(const float4*)(x + off + 4);
  float4 ra, rb;
  ra.x = fmaf(fmaf(w0, p0a.x, w1 * p1a.x), inv, xa.x);
  ra.y = fmaf(fmaf(w0, p0a.y, w1 * p1a.y), inv, xa.y);
  ra.z = fmaf(fmaf(w0, p0a.z, w1 * p1a.z), inv, xa.z);
  ra.w = fmaf(fmaf(w0, p0a.w, w1 * p1a.w), inv, xa.w);
  rb.x = fmaf(fmaf(w0, p0b.x, w1 * p1b.x), inv, xb.x);
  rb.y = fmaf(fmaf(w0, p0b.y, w1 * p1b.y), inv, xb.y);
  rb.z = fmaf(fmaf(w0, p0b.z, w1 * p1b.z), inv, xb.z);
  rb.w = fmaf(fmaf(w0, p0b.w, w1 * p1b.w), inv, xb.w);
  *(float4*)(out + off)     = ra;
  *(float4*)(out + off + 4) = rb;
}

// ---------------------------------------------------------------- launch
extern "C" void kernel_launch(void* const* d_in, const int* in_sizes, int n_in,
                              void* d_out, int out_size, void* d_ws, size_t ws_size,
                              hipStream_t stream)
{
  const float* x  = (const float*)d_in[0];
  const float* wq = (const float*)d_in[1];
  const float* bq = (const float*)d_in[2];
  const float* wk = (const float*)d_in[3];
  const float* bk = (const float*)d_in[4];
  const float* wv = (const float*)d_in[5];
  const float* bv = (const float*)d_in[6];
  const float* gm = (const float*)d_in[7];

  // ws layout (~13.3 MB):
  //  [0, 512K)    Qb bf16 [4][4096][16]   (pre-scaled by log2e)
  //  [512K, 1M)   Kb bf16 [4][4096][16]
  //  [1M, 5M)     Vt bf16 [4][128][4096]
  //  [5M, 13M)    O1 f32  [4][4096][128]  (ks=1 partial; ks=0 lives in d_out)
  //  [13M, +256K) ML f32x2 [2][4][4096]
  char* w = (char*)d_ws;
  u16*    Qb = (u16*)(w);
  u16*    Kb = (u16*)(w + (512ll << 10));
  u16*    Vt = (u16*)(w + (1ll << 20));
  float*  O1 = (float*)(w + (5ll << 20));
  float2* MLp = (float2*)(w + (13ll << 20));
  float*  out = (float*)d_out;

  qkv_proj<<<128, 256, 0, stream>>>(x, wq, bq, wk, bk, wv, bv, Qb, Kb, Vt);
  attn<<<256, 256, 0, stream>>>(Qb, Kb, Vt, out, O1, MLp);
  combine<<<1024, 256, 0, stream>>>(O1, MLp, x, gm, out);
}

// Round 4
// 74.043 us; speedup vs baseline: 2.7658x; 1.1414x over previous
//
#include <hip/hip_runtime.h>
#include <hip/hip_bf16.h>

// SAGAN self-attention, MI355X (gfx950).
// B=4, N=4096 (64x64), C=128, d_qk=16. out = gamma * softmax(QK^T) V + x.
//
//  k1 qkv_proj : MFMA GEMM x[16384,128] @ [wq|wk|wv] -> Qb,Kb bf16 [4,4096,16],
//                Vt bf16 [4,128,4096] (transposed). Q pre-scaled by log2(e).
//  k2 attn     : flash attention, mfma_f32_32x32x16_bf16, swapped QK^T,
//                in-register softmax (exp2-direct, permlane32 cross-half reduce),
//                P->bf16 + permlane32_swap, k-split=NKS partials.
//  k3 combine  : merge NKS partials with (m,l), * gamma + x -> d_out.

typedef __attribute__((ext_vector_type(4)))  short short4v;
typedef __attribute__((ext_vector_type(8)))  short short8;
typedef __attribute__((ext_vector_type(16))) float f32x16;
typedef unsigned short u16;

#define LOG2E 1.4426950408889634f

__device__ __forceinline__ u16 f2bf(float f) {
  __hip_bfloat16 h = __float2bfloat16(f);
  return __builtin_bit_cast(u16, h);
}
__device__ __forceinline__ unsigned pk2bf(float lo, float hi) {
  return (unsigned)f2bf(lo) | ((unsigned)f2bf(hi) << 16);
}
__device__ __forceinline__ float max3f(float a, float b, float c) {
  return fmaxf(fmaxf(a, b), c);          // fuses to v_max3_f32 (T17)
}
// cross-half (lane i <-> i+32) reduce via permlane32_swap: pure VALU, no DS latency
__device__ __forceinline__ float xhalf_max(float x) {
  float a = x, b = x;
  asm("v_permlane32_swap_b32 %0, %1" : "+v"(a), "+v"(b));
  return fmaxf(a, b);
}
__device__ __forceinline__ float xhalf_sum(float x) {
  float a = x, b = x;
  asm("v_permlane32_swap_b32 %0, %1" : "+v"(a), "+v"(b));
  return a + b;
}

// ---------------------------------------------------------------- kernel 1
// grid 128 = b(4) x rt(32): block computes rows [rt*128, +128) of batch b.
__global__ __launch_bounds__(256) void qkv_proj(
    const float* __restrict__ x,
    const float* __restrict__ wq, const float* __restrict__ bq,
    const float* __restrict__ wk, const float* __restrict__ bk,
    const float* __restrict__ wv, const float* __restrict__ bv,
    u16* __restrict__ Qb, u16* __restrict__ Kb, u16* __restrict__ Vt)
{
  __shared__ u16 xs[128 * 136];
  __shared__ u16 ws[160 * 136];
  const int tid = threadIdx.x;
  const int b   = blockIdx.x >> 5;
  const int n0  = (blockIdx.x & 31) * 128;

  const float4* xg = (const float4*)(x + ((size_t)b * 4096 + n0) * 128);
#pragma unroll
  for (int p = 0; p < 16; ++p) {
    int idx = tid + p * 256;              // 4096 float4s
    float4 v = xg[idx];
    int n = idx >> 5, i4 = idx & 31;
    short4v pk;
    pk[0] = (short)f2bf(v.x); pk[1] = (short)f2bf(v.y);
    pk[2] = (short)f2bf(v.z); pk[3] = (short)f2bf(v.w);
    *(short4v*)(xs + n * 136 + i4 * 4) = pk;
  }
#pragma unroll
  for (int p = 0; p < 8; ++p) {
    int idx = tid + p * 256;              // 2048 = 128x16
    int k = idx >> 4, d = idx & 15;
    ws[d * 136 + k]        = f2bf(wq[idx] * LOG2E);
    ws[(16 + d) * 136 + k] = f2bf(wk[idx]);
  }
#pragma unroll
  for (int p = 0; p < 64; ++p) {
    int idx = tid + p * 256;              // 16384 = 128x128
    int k = idx >> 7, c = idx & 127;
    ws[(32 + c) * 136 + k] = f2bf(wv[idx]);
  }
  __syncthreads();

  const int lane = tid & 63, wid = tid >> 6;
  const int ln31 = lane & 31, hi = lane >> 5;

#pragma unroll
  for (int j = 0; j < 5; ++j) {
    int t  = wid + j * 4;                 // 0..19
    int mt = t / 5, nt = t % 5;
    const u16* arow = xs + (mt * 32 + ln31) * 136 + hi * 8;
    const u16* brow = ws + (nt * 32 + ln31) * 136 + hi * 8;
    f32x16 acc = (f32x16)0.0f;
#pragma unroll
    for (int ks = 0; ks < 8; ++ks) {
      short8 a = *(const short8*)(arow + ks * 16);
      short8 w = *(const short8*)(brow + ks * 16);
      acc = __builtin_amdgcn_mfma_f32_32x32x16_bf16(a, w, acc, 0, 0, 0);
    }
    if (nt == 0) {
      float bias = (ln31 < 16) ? bq[ln31] * LOG2E : bk[ln31 & 15];
      u16* base = ((ln31 < 16) ? Qb : Kb)
                + ((size_t)b * 4096 + n0 + mt * 32) * 16 + (ln31 & 15);
#pragma unroll
      for (int r = 0; r < 16; ++r) {
        int nl = (r & 3) + 8 * (r >> 2) + 4 * hi;   // C/D row map
        base[nl * 16] = f2bf(acc[r] + bias);
      }
    } else {
      int c = (nt - 1) * 32 + ln31;
      float bias = bv[c];
      u16* vb = Vt + ((size_t)b * 128 + c) * 4096 + n0 + mt * 32 + 4 * hi;
#pragma unroll
      for (int g = 0; g < 4; ++g) {
        short4v pk;
        pk[0] = (short)f2bf(acc[g*4+0] + bias);
        pk[1] = (short)f2bf(acc[g*4+1] + bias);
        pk[2] = (short)f2bf(acc[g*4+2] + bias);
        pk[3] = (short)f2bf(acc[g*4+3] + bias);
        *(short4v*)(vb + 8 * g) = pk;
      }
    }
  }
}

// ---------------------------------------------------------------- kernel 2
// grid 4*32*NKS. block 256 = 4 waves, wave owns 32 q-rows (128 q/block).
// Block handles k range [ks*4096/NKS, +4096/NKS) in 64-k chunks.
template<int NKS>
__global__ __launch_bounds__(256) void attn(
    const u16* __restrict__ Qb, const u16* __restrict__ Kb,
    const u16* __restrict__ Vt,
    float* __restrict__ O0, float* __restrict__ O1,
    float* __restrict__ O2, float* __restrict__ O3,
    float2* __restrict__ ML)
{
  // per buffer: V 128 rows x 144B = 18432, K 64 rows x 48B = 3072
  __shared__ __align__(16) char sm[2][21504];
  const int tid  = threadIdx.x;
  const int lane = tid & 63;
  const int wid  = tid >> 6;
  const int ln31 = lane & 31;
  const int hi   = lane >> 5;

  constexpr int KSH    = (NKS == 4) ? 2 : 1;
  constexpr int CHUNKS = 64 / NKS;        // 64-k chunks per block
  const int b   = blockIdx.x >> (5 + KSH);
  const int qt  = (blockIdx.x >> KSH) & 31;
  const int ks  = blockIdx.x & (NKS - 1);
  const int qw  = qt * 128 + wid * 32;    // wave's first q row (within batch)
  const int kb0 = ks * (4096 / NKS);

  // Q B-fragment: col q = ln31, d = hi*8 + j (Q pre-scaled by log2e)
  const short8 qf = *(const short8*)(Qb + (((size_t)b * 4096 + qw + ln31) << 4) + (hi << 3));

  f32x16 acc[4];
#pragma unroll
  for (int ct = 0; ct < 4; ++ct) acc[ct] = (f32x16)0.0f;
  float m = -1e30f, l = 0.f;

  const char* vg = (const char*)(Vt + (size_t)b * 128 * 4096);
  const char* kg = (const char*)(Kb + (size_t)b * 4096 * 16);
  const int vc = tid >> 1;                // V channel row this thread stages
  const int vp = tid & 1;                 // which 64B half of the 128B row

  uint4 rv0, rv1, rv2, rv3, rk;

  auto loadChunk = [&](int kb) {          // global -> regs (issued early, T14)
    const char* vs = vg + (size_t)vc * 8192 + (size_t)kb * 2 + vp * 64;
    rv0 = *(const uint4*)(vs);
    rv1 = *(const uint4*)(vs + 16);
    rv2 = *(const uint4*)(vs + 32);
    rv3 = *(const uint4*)(vs + 48);
    if (tid < 128)
      rk = *(const uint4*)(kg + (size_t)(kb + (tid >> 1)) * 32 + (tid & 1) * 16);
  };
  auto storeChunk = [&](char* buf) {      // regs -> LDS (after compute)
    char* vd = buf + vc * 144 + vp * 64;
    *(uint4*)(vd)      = rv0;
    *(uint4*)(vd + 16) = rv1;
    *(uint4*)(vd + 32) = rv2;
    *(uint4*)(vd + 48) = rv3;
    if (tid < 128)
      *(uint4*)(buf + 18432 + (tid >> 1) * 48 + (tid & 1) * 16) = rk;
  };

  auto compute = [&](const char* buf) {
    const char* kbuf = buf + 18432;
#pragma unroll
    for (int kt = 0; kt < 2; ++kt) {      // two 32-k subtiles per 64-k chunk
      // swapped QK^T: A = K rows (kk = ln31), B = Q -> D[kk][q], lane col = q
      short8 kf = *(const short8*)(kbuf + (kt * 32 + ln31) * 48 + hi * 16);
      f32x16 s = __builtin_amdgcn_mfma_f32_32x32x16_bf16(kf, qf, (f32x16)0.0f, 0, 0, 0);

      // online softmax (log2 space): s[r] is kk = (r&3)+8*(r>>2)+4*hi
      float t0 = max3f(s[0], s[1], s[2]),  t1 = max3f(s[3], s[4], s[5]);
      float t2 = max3f(s[6], s[7], s[8]),  t3 = max3f(s[9], s[10], s[11]);
      float t4 = max3f(s[12], s[13], s[14]);
      float pmax = fmaxf(max3f(t0, t1, t2), max3f(t3, t4, s[15]));
      pmax = xhalf_max(pmax);
      if (__any(pmax > m + 8.0f)) {       // defer-max (T13), wave-uniform branch
        float mn = fmaxf(m, pmax);
        float al = exp2f(m - mn);
        l *= al;
        m  = mn;
#pragma unroll
        for (int r = 0; r < 16; ++r) {
          float ar = __shfl(al, (r & 3) + 8 * (r >> 2) + 4 * hi); // alpha of acc-row q
          acc[0][r] *= ar; acc[1][r] *= ar; acc[2][r] *= ar; acc[3][r] *= ar;
        }
      }
      float p[16];
      float rs = 0.f;
#pragma unroll
      for (int r = 0; r < 16; ++r) { p[r] = exp2f(s[r] - m); rs += p[r]; }
      l += xhalf_sum(rs);

      // P -> bf16 PV A-fragments: packed pairs + permlane32_swap (T12)
      unsigned u0 = pk2bf(p[0], p[1]),  u1 = pk2bf(p[2], p[3]);
      unsigned u2 = pk2bf(p[4], p[5]),  u3 = pk2bf(p[6], p[7]);
      asm("v_permlane32_swap_b32 %0, %1" : "+v"(u0), "+v"(u2));
      asm("v_permlane32_swap_b32 %0, %1" : "+v"(u1), "+v"(u3));
      unsigned y0 = pk2bf(p[8], p[9]),   y1 = pk2bf(p[10], p[11]);
      unsigned y2 = pk2bf(p[12], p[13]), y3 = pk2bf(p[14], p[15]);
      asm("v_permlane32_swap_b32 %0, %1" : "+v"(y0), "+v"(y2));
      asm("v_permlane32_swap_b32 %0, %1" : "+v"(y1), "+v"(y3));
      union { unsigned u[4]; short8 s8; } pa0, pa1;
      pa0.u[0] = u0; pa0.u[1] = u1; pa0.u[2] = u2; pa0.u[3] = u3;
      pa1.u[0] = y0; pa1.u[1] = y1; pa1.u[2] = y2; pa1.u[3] = y3;

      // PV: acc[ct] += P[32q x 32k] @ V[32k x 32c] (two K=16 MFMAs per ct)
      __builtin_amdgcn_s_setprio(1);
#pragma unroll
      for (int ct = 0; ct < 4; ++ct) {
        const char* vrow = buf + (ct * 32 + ln31) * 144 + kt * 64 + hi * 16;
        short8 vf0 = *(const short8*)(vrow);        // k 0..15 of subtile
        short8 vf1 = *(const short8*)(vrow + 32);   // k 16..31
        acc[ct] = __builtin_amdgcn_mfma_f32_32x32x16_bf16(pa0.s8, vf0, acc[ct], 0, 0, 0);
        acc[ct] = __builtin_amdgcn_mfma_f32_32x32x16_bf16(pa1.s8, vf1, acc[ct], 0, 0, 0);
      }
      __builtin_amdgcn_s_setprio(0);
    }
  };

  loadChunk(kb0);
  storeChunk(sm[0]);
  __syncthreads();
#pragma unroll 1
  for (int it = 0; it < CHUNKS; ++it) {
    if (it < CHUNKS - 1) loadChunk(kb0 + (it + 1) * 64);
    compute(sm[it & 1]);
    if (it < CHUNKS - 1) storeChunk(sm[(it + 1) & 1]);
    __syncthreads();                      // single barrier per iter (dbuf)
  }

  // epilogue: store partial (un-normalized) O and (m, l)
  if (lane < 32)
    ML[(size_t)ks * 16384 + (size_t)b * 4096 + qw + lane] = make_float2(m, l);
  float* Op = (ks == 0) ? O0 : (ks == 1) ? O1 : (ks == 2) ? O2 : O3;
  Op += ((size_t)b * 4096 + qw) * 128;
#pragma unroll
  for (int ct = 0; ct < 4; ++ct) {
#pragma unroll
    for (int r = 0; r < 16; ++r) {
      int q = (r & 3) + 8 * (r >> 2) + 4 * hi;     // C/D row map (m74/m101)
      Op[(size_t)q * 128 + ct * 32 + ln31] = acc[ct][r];
    }
  }
}

// ---------------------------------------------------------------- kernel 3
template<int NKS>
__global__ __launch_bounds__(256) void combine(
    const float* __restrict__ O1, const float* __restrict__ O2,
    const float* __restrict__ O3, const float2* __restrict__ ML,
    const float* __restrict__ x, const float* __restrict__ gamma,
    float* __restrict__ out)   // out currently holds the ks=0 partial
{
  int i    = blockIdx.x * 256 + threadIdx.x;   // 0..262143
  int nrow = i >> 4;
  int c0   = (i & 15) << 3;
  const float* Ops[4] = {out, O1, O2, O3};

  float2 ml[NKS];
  float M = -1e30f;
#pragma unroll
  for (int p = 0; p < NKS; ++p) { ml[p] = ML[(size_t)p * 16384 + nrow]; M = fmaxf(M, ml[p].x); }
  float wsum = 0.f, wgt[NKS];
#pragma unroll
  for (int p = 0; p < NKS; ++p) { wgt[p] = exp2f(ml[p].x - M); wsum = fmaf(wgt[p], ml[p].y, wsum); }
  float inv = gamma[0] / wsum;

  size_t off = (size_t)nrow * 128 + c0;
  float accv[8];
#pragma unroll
  for (int j = 0; j < 8; ++j) accv[j] = 0.f;
#pragma unroll
  for (int p = 0; p < NKS; ++p) {
    float4 a = *(const float4*)(Ops[p] + off);
    float4 b = *(const float4*)(Ops[p] + off + 4);
    accv[0] = fmaf(wgt[p], a.x, accv[0]); accv[1] = fmaf(wgt[p], a.y, accv[1]);
    accv[2] = fmaf(wgt[p], a.z, accv[2]); accv[3] = fmaf(wgt[p], a.w, accv[3]);
    accv[4] = fmaf(wgt[p], b.x, accv[4]); accv[5] = fmaf(wgt[p], b.y, accv[5]);
    accv[6] = fmaf(wgt[p], b.z, accv[6]); accv[7] = fmaf(wgt[p], b.w, accv[7]);
  }
  float4 xa = *(const float4*)(x + off);
  float4 xb = *(const float4*)(x + off + 4);
  float4 ra, rb;
  ra.x = fmaf(accv[0], inv, xa.x); ra.y = fmaf(accv[1], inv, xa.y);
  ra.z = fmaf(accv[2], inv, xa.z); ra.w = fmaf(accv[3], inv, xa.w);
  rb.x = fmaf(accv[4], inv, xb.x); rb.y = fmaf(accv[5], inv, xb.y);
  rb.z = fmaf(accv[6], inv, xb.z); rb.w = fmaf(accv[7], inv, xb.w);
  *(float4*)(out + off)     = ra;
  *(float4*)(out + off + 4) = rb;
}

// ---------------------------------------------------------------- launch
extern "C" void kernel_launch(void* const* d_in, const int* in_sizes, int n_in,
                              void* d_out, int out_size, void* d_ws, size_t ws_size,
                              hipStream_t stream)
{
  const float* x  = (const float*)d_in[0];
  const float* wq = (const float*)d_in[1];
  const float* bq = (const float*)d_in[2];
  const float* wk = (const float*)d_in[3];
  const float* bk = (const float*)d_in[4];
  const float* wv = (const float*)d_in[5];
  const float* bv = (const float*)d_in[6];
  const float* gm = (const float*)d_in[7];

  // ws layout:
  //  [0, 512K)    Qb bf16 [4][4096][16]   (pre-scaled by log2e)
  //  [512K, 1M)   Kb bf16 [4][4096][16]
  //  [1M, 5M)     Vt bf16 [4][128][4096]
  //  [5M..29M)    O1..O3 f32 partials (8 MB each; O0 lives in d_out)
  //  then ML f32x2 [NKS][16384]
  char* w = (char*)d_ws;
  u16*   Qb = (u16*)(w);
  u16*   Kb = (u16*)(w + (512ll << 10));
  u16*   Vt = (u16*)(w + (1ll << 20));
  float* O1 = (float*)(w + (5ll << 20));
  float* O2 = (float*)(w + (13ll << 20));
  float* O3 = (float*)(w + (21ll << 20));
  float* out = (float*)d_out;

  qkv_proj<<<128, 256, 0, stream>>>(x, wq, bq, wk, bk, wv, bv, Qb, Kb, Vt);

  const size_t need4 = (29ll << 20) + (4ll * 16384 * sizeof(float2));
  if (ws_size >= need4) {
    float2* MLp = (float2*)(w + (29ll << 20));
    attn<4><<<512, 256, 0, stream>>>(Qb, Kb, Vt, out, O1, O2, O3, MLp);
    combine<4><<<1024, 256, 0, stream>>>(O1, O2, O3, MLp, x, gm, out);
  } else {
    float2* MLp = (float2*)(w + (13ll << 20));
    attn<2><<<256, 256, 0, stream>>>(Qb, Kb, Vt, out, O1, O1, O1, MLp);
    combine<2><<<1024, 256, 0, stream>>>(O1, O1, O1, MLp, x, gm, out);
  }
}

// Round 5
// 64.996 us; speedup vs baseline: 3.1507x; 1.1392x over previous
//
#include <hip/hip_runtime.h>
#include <hip/hip_bf16.h>

// SAGAN self-attention, MI355X (gfx950).
// B=4, H=W=64 (N=4096), C=128, d_qk=16. out = gamma * softmax(QK^T) V + x.
//
//  k1 qkv_proj : MFMA GEMM x[16384,128] @ [wq|wk|wv] -> Qb,Kb bf16 [4,4096,16],
//                Vt bf16 [4,128,4096] (transposed). Q pre-scaled by log2(e).
//  k2 attn     : flash attention, mfma_f32_32x32x16_bf16, swapped QK^T.
//                NO max tracking: p = exp2(s - 16) (safe: |s|log2e <~ 40 << 127,
//                softmax shift-invariant; bias folded into the QK MFMA C operand).
//                l deferred to epilogue (lane-local sums + one permlane swap).
//                K loaded global->reg (L2-resident, prefetched); LDS = V only.
//                k-split=NKS partials; ks=0 partial in d_out, rest in ws.
//  k3 combine  : out = gamma * (sum_p O_p) / (sum_p l_p) + x.

typedef __attribute__((ext_vector_type(4)))  short short4v;
typedef __attribute__((ext_vector_type(8)))  short short8;
typedef __attribute__((ext_vector_type(16))) float f32x16;
typedef unsigned short u16;

#define LOG2E 1.4426950408889634f

__device__ __forceinline__ u16 f2bf(float f) {
  __hip_bfloat16 h = __float2bfloat16(f);
  return __builtin_bit_cast(u16, h);
}
__device__ __forceinline__ unsigned pk2bf(float lo, float hi) {
  return (unsigned)f2bf(lo) | ((unsigned)f2bf(hi) << 16);
}
// cross-half (lane i <-> i+32) sum via permlane32_swap: pure VALU, no DS latency
__device__ __forceinline__ float xhalf_sum(float x) {
  float a = x, b = x;
  asm("v_permlane32_swap_b32 %0, %1" : "+v"(a), "+v"(b));
  return a + b;
}

// ---------------------------------------------------------------- kernel 1
// grid 128 = b(4) x rt(32): block computes rows [rt*128, +128) of batch b.
__global__ __launch_bounds__(256) void qkv_proj(
    const float* __restrict__ x,
    const float* __restrict__ wq, const float* __restrict__ bq,
    const float* __restrict__ wk, const float* __restrict__ bk,
    const float* __restrict__ wv, const float* __restrict__ bv,
    u16* __restrict__ Qb, u16* __restrict__ Kb, u16* __restrict__ Vt)
{
  __shared__ u16 xs[128 * 136];
  __shared__ u16 ws[160 * 136];
  const int tid = threadIdx.x;
  const int b   = blockIdx.x >> 5;
  const int n0  = (blockIdx.x & 31) * 128;

  const float4* xg = (const float4*)(x + ((size_t)b * 4096 + n0) * 128);
#pragma unroll
  for (int p = 0; p < 16; ++p) {
    int idx = tid + p * 256;              // 4096 float4s
    float4 v = xg[idx];
    int n = idx >> 5, i4 = idx & 31;
    short4v pk;
    pk[0] = (short)f2bf(v.x); pk[1] = (short)f2bf(v.y);
    pk[2] = (short)f2bf(v.z); pk[3] = (short)f2bf(v.w);
    *(short4v*)(xs + n * 136 + i4 * 4) = pk;
  }
#pragma unroll
  for (int p = 0; p < 8; ++p) {
    int idx = tid + p * 256;              // 2048 = 128x16
    int k = idx >> 4, d = idx & 15;
    ws[d * 136 + k]        = f2bf(wq[idx] * LOG2E);
    ws[(16 + d) * 136 + k] = f2bf(wk[idx]);
  }
#pragma unroll
  for (int p = 0; p < 64; ++p) {
    int idx = tid + p * 256;              // 16384 = 128x128
    int k = idx >> 7, c = idx & 127;
    ws[(32 + c) * 136 + k] = f2bf(wv[idx]);
  }
  __syncthreads();

  const int lane = tid & 63, wid = tid >> 6;
  const int ln31 = lane & 31, hi = lane >> 5;

#pragma unroll
  for (int j = 0; j < 5; ++j) {
    int t  = wid + j * 4;                 // 0..19
    int mt = t / 5, nt = t % 5;
    const u16* arow = xs + (mt * 32 + ln31) * 136 + hi * 8;
    const u16* brow = ws + (nt * 32 + ln31) * 136 + hi * 8;
    f32x16 acc = (f32x16)0.0f;
#pragma unroll
    for (int ks = 0; ks < 8; ++ks) {
      short8 a = *(const short8*)(arow + ks * 16);
      short8 w = *(const short8*)(brow + ks * 16);
      acc = __builtin_amdgcn_mfma_f32_32x32x16_bf16(a, w, acc, 0, 0, 0);
    }
    if (nt == 0) {
      float bias = (ln31 < 16) ? bq[ln31] * LOG2E : bk[ln31 & 15];
      u16* base = ((ln31 < 16) ? Qb : Kb)
                + ((size_t)b * 4096 + n0 + mt * 32) * 16 + (ln31 & 15);
#pragma unroll
      for (int r = 0; r < 16; ++r) {
        int nl = (r & 3) + 8 * (r >> 2) + 4 * hi;   // C/D row map
        base[nl * 16] = f2bf(acc[r] + bias);
      }
    } else {
      int c = (nt - 1) * 32 + ln31;
      float bias = bv[c];
      u16* vb = Vt + ((size_t)b * 128 + c) * 4096 + n0 + mt * 32 + 4 * hi;
#pragma unroll
      for (int g = 0; g < 4; ++g) {
        short4v pk;
        pk[0] = (short)f2bf(acc[g*4+0] + bias);
        pk[1] = (short)f2bf(acc[g*4+1] + bias);
        pk[2] = (short)f2bf(acc[g*4+2] + bias);
        pk[3] = (short)f2bf(acc[g*4+3] + bias);
        *(short4v*)(vb + 8 * g) = pk;
      }
    }
  }
}

// ---------------------------------------------------------------- kernel 2
// grid 4*32*NKS. block 256 = 4 waves, wave owns 32 q-rows (128 q/block).
// Block handles k range [ks*4096/NKS, +4096/NKS) in 64-k chunks.
template<int NKS>
__global__ __launch_bounds__(256) void attn(
    const u16* __restrict__ Qb, const u16* __restrict__ Kb,
    const u16* __restrict__ Vt,
    float* __restrict__ O0, float* __restrict__ O1,
    float* __restrict__ O2, float* __restrict__ O3,
    float* __restrict__ Lp)
{
  // per buffer: V 128 rows x 144B (64 k bf16 + 16B pad) = 18432
  __shared__ __align__(16) char sm[2][18432];
  const int tid  = threadIdx.x;
  const int lane = tid & 63;
  const int wid  = tid >> 6;
  const int ln31 = lane & 31;
  const int hi   = lane >> 5;

  constexpr int KSH    = (NKS == 4) ? 2 : 1;
  constexpr int CHUNKS = 64 / NKS;        // 64-k chunks per block
  const int b   = blockIdx.x >> (5 + KSH);
  const int qt  = (blockIdx.x >> KSH) & 31;
  const int ks  = blockIdx.x & (NKS - 1);
  const int qw  = qt * 128 + wid * 32;    // wave's first q row (within batch)
  const int kb0 = ks * (4096 / NKS);

  // Q B-fragment: col q = ln31, d = hi*8 + j (Q pre-scaled by log2e)
  const short8 qf = *(const short8*)(Qb + (((size_t)b * 4096 + qw + ln31) << 4) + (hi << 3));

  f32x16 acc[4];
#pragma unroll
  for (int ct = 0; ct < 4; ++ct) acc[ct] = (f32x16)0.0f;
  float lacc = 0.f;
  const f32x16 cbias = (f32x16)(-16.0f);  // s = q.k*log2e - 16, free in MFMA C

  const char* vg = (const char*)(Vt + (size_t)b * 128 * 4096);
  const char* kg = (const char*)(Kb + (size_t)b * 4096 * 16);
  const int vc = tid >> 1;                // V channel row this thread stages
  const int vp = tid & 1;                 // which 64B half of the 128B row

  uint4 rv0, rv1, rv2, rv3;               // V staging regs (T14 split)
  uint4 rkc0, rkc1, rkn0, rkn1;           // K fragments: current / next chunk

  auto loadV = [&](int kb) {              // global -> regs (issued early)
    const char* vs = vg + (size_t)vc * 8192 + (size_t)kb * 2 + vp * 64;
    rv0 = *(const uint4*)(vs);
    rv1 = *(const uint4*)(vs + 16);
    rv2 = *(const uint4*)(vs + 32);
    rv3 = *(const uint4*)(vs + 48);
  };
  auto loadK = [&](int kb, uint4& k0, uint4& k1) {  // direct to regs, coalesced
    const char* kr = kg + (size_t)(kb + ln31) * 32 + hi * 16;
    k0 = *(const uint4*)(kr);             // kt=0 rows
    k1 = *(const uint4*)(kr + 1024);      // kt=1 rows (+32 rows * 32B)
  };
  auto storeV = [&](char* buf) {          // regs -> LDS (after compute)
    char* vd = buf + vc * 144 + vp * 64;
    *(uint4*)(vd)      = rv0;
    *(uint4*)(vd + 16) = rv1;
    *(uint4*)(vd + 32) = rv2;
    *(uint4*)(vd + 48) = rv3;
  };

  auto compute = [&](const char* buf, uint4 k0, uint4 k1) {
#pragma unroll
    for (int kt = 0; kt < 2; ++kt) {      // two independent 32-k subtiles
      // swapped QK^T: A = K rows (kk = ln31), B = Q -> D[kk][q], lane col = q
      short8 kf = __builtin_bit_cast(short8, kt ? k1 : k0);
      f32x16 s = __builtin_amdgcn_mfma_f32_32x32x16_bf16(kf, qf, cbias, 0, 0, 0);

      // p = exp2(s) directly; s[r] is kk = (r&3)+8*(r>>2)+4*hi
      float p[16];
#pragma unroll
      for (int r = 0; r < 16; ++r) p[r] = exp2f(s[r]);
      // tree sum (depth 4), deferred cross-half to epilogue
      float a0 = p[0]+p[1],  a1 = p[2]+p[3],  a2 = p[4]+p[5],  a3 = p[6]+p[7];
      float b0 = p[8]+p[9],  b1 = p[10]+p[11], b2 = p[12]+p[13], b3 = p[14]+p[15];
      lacc += ((a0+a1)+(a2+a3)) + ((b0+b1)+(b2+b3));

      // P -> bf16 PV A-fragments: packed pairs + permlane32_swap (T12)
      unsigned u0 = pk2bf(p[0], p[1]),  u1 = pk2bf(p[2], p[3]);
      unsigned u2 = pk2bf(p[4], p[5]),  u3 = pk2bf(p[6], p[7]);
      asm("v_permlane32_swap_b32 %0, %1" : "+v"(u0), "+v"(u2));
      asm("v_permlane32_swap_b32 %0, %1" : "+v"(u1), "+v"(u3));
      unsigned y0 = pk2bf(p[8], p[9]),   y1 = pk2bf(p[10], p[11]);
      unsigned y2 = pk2bf(p[12], p[13]), y3 = pk2bf(p[14], p[15]);
      asm("v_permlane32_swap_b32 %0, %1" : "+v"(y0), "+v"(y2));
      asm("v_permlane32_swap_b32 %0, %1" : "+v"(y1), "+v"(y3));
      union { unsigned u[4]; short8 s8; } pa0, pa1;
      pa0.u[0] = u0; pa0.u[1] = u1; pa0.u[2] = u2; pa0.u[3] = u3;
      pa1.u[0] = y0; pa1.u[1] = y1; pa1.u[2] = y2; pa1.u[3] = y3;

      // PV: acc[ct] += P[32q x 32k] @ V[32k x 32c] (two K=16 MFMAs per ct)
      __builtin_amdgcn_s_setprio(1);
#pragma unroll
      for (int ct = 0; ct < 4; ++ct) {
        const char* vrow = buf + (ct * 32 + ln31) * 144 + kt * 64 + hi * 16;
        short8 vf0 = *(const short8*)(vrow);        // k 0..15 of subtile
        short8 vf1 = *(const short8*)(vrow + 32);   // k 16..31
        acc[ct] = __builtin_amdgcn_mfma_f32_32x32x16_bf16(pa0.s8, vf0, acc[ct], 0, 0, 0);
        acc[ct] = __builtin_amdgcn_mfma_f32_32x32x16_bf16(pa1.s8, vf1, acc[ct], 0, 0, 0);
      }
      __builtin_amdgcn_s_setprio(0);
    }
  };

  loadV(kb0);
  loadK(kb0, rkc0, rkc1);
  storeV(sm[0]);
  __syncthreads();
#pragma unroll 1
  for (int it = 0; it < CHUNKS; ++it) {
    if (it < CHUNKS - 1) {                // prefetch next chunk (V + K) early
      loadV(kb0 + (it + 1) * 64);
      loadK(kb0 + (it + 1) * 64, rkn0, rkn1);
    }
    compute(sm[it & 1], rkc0, rkc1);
    if (it < CHUNKS - 1) storeV(sm[(it + 1) & 1]);
    __syncthreads();                      // single barrier per iter (dbuf)
    rkc0 = rkn0; rkc1 = rkn1;
  }

  // epilogue: cross-half l reduce, store partial O and l
  float lt = xhalf_sum(lacc);
  if (lane < 32)
    Lp[(size_t)ks * 16384 + (size_t)b * 4096 + qw + lane] = lt;
  float* Op = (ks == 0) ? O0 : (ks == 1) ? O1 : (ks == 2) ? O2 : O3;
  Op += ((size_t)b * 4096 + qw) * 128;
#pragma unroll
  for (int ct = 0; ct < 4; ++ct) {
#pragma unroll
    for (int r = 0; r < 16; ++r) {
      int q = (r & 3) + 8 * (r >> 2) + 4 * hi;     // C/D row map (m74/m101)
      Op[(size_t)q * 128 + ct * 32 + ln31] = acc[ct][r];
    }
  }
}

// ---------------------------------------------------------------- kernel 3
template<int NKS>
__global__ __launch_bounds__(256) void combine(
    const float* __restrict__ O1, const float* __restrict__ O2,
    const float* __restrict__ O3, const float* __restrict__ Lp,
    const float* __restrict__ x, const float* __restrict__ gamma,
    float* __restrict__ out)   // out currently holds the ks=0 partial
{
  int i    = blockIdx.x * 256 + threadIdx.x;   // 0..262143
  int nrow = i >> 4;
  int c0   = (i & 15) << 3;
  const float* Ops[4] = {out, O1, O2, O3};

  float wsum = 0.f;
#pragma unroll
  for (int p = 0; p < NKS; ++p) wsum += Lp[(size_t)p * 16384 + nrow];
  float inv = gamma[0] / wsum;

  size_t off = (size_t)nrow * 128 + c0;
  float accv[8];
#pragma unroll
  for (int j = 0; j < 8; ++j) accv[j] = 0.f;
#pragma unroll
  for (int p = 0; p < NKS; ++p) {
    float4 a = *(const float4*)(Ops[p] + off);
    float4 b = *(const float4*)(Ops[p] + off + 4);
    accv[0] += a.x; accv[1] += a.y; accv[2] += a.z; accv[3] += a.w;
    accv[4] += b.x; accv[5] += b.y; accv[6] += b.z; accv[7] += b.w;
  }
  float4 xa = *(const float4*)(x + off);
  float4 xb = *(const float4*)(x + off + 4);
  float4 ra, rb;
  ra.x = fmaf(accv[0], inv, xa.x); ra.y = fmaf(accv[1], inv, xa.y);
  ra.z = fmaf(accv[2], inv, xa.z); ra.w = fmaf(accv[3], inv, xa.w);
  rb.x = fmaf(accv[4], inv, xb.x); rb.y = fmaf(accv[5], inv, xb.y);
  rb.z = fmaf(accv[6], inv, xb.z); rb.w = fmaf(accv[7], inv, xb.w);
  *(float4*)(out + off)     = ra;
  *(float4*)(out + off + 4) = rb;
}

// ---------------------------------------------------------------- launch
extern "C" void kernel_launch(void* const* d_in, const int* in_sizes, int n_in,
                              void* d_out, int out_size, void* d_ws, size_t ws_size,
                              hipStream_t stream)
{
  const float* x  = (const float*)d_in[0];
  const float* wq = (const float*)d_in[1];
  const float* bq = (const float*)d_in[2];
  const float* wk = (const float*)d_in[3];
  const float* bk = (const float*)d_in[4];
  const float* wv = (const float*)d_in[5];
  const float* bv = (const float*)d_in[6];
  const float* gm = (const float*)d_in[7];

  // ws layout:
  //  [0, 512K)    Qb bf16 [4][4096][16]   (pre-scaled by log2e)
  //  [512K, 1M)   Kb bf16 [4][4096][16]
  //  [1M, 5M)     Vt bf16 [4][128][4096]
  //  [5M..29M)    O1..O3 f32 partials (8 MB each; O0 lives in d_out)
  //  then Lp f32 [NKS][16384]
  char* w = (char*)d_ws;
  u16*   Qb = (u16*)(w);
  u16*   Kb = (u16*)(w + (512ll << 10));
  u16*   Vt = (u16*)(w + (1ll << 20));
  float* O1 = (float*)(w + (5ll << 20));
  float* O2 = (float*)(w + (13ll << 20));
  float* O3 = (float*)(w + (21ll << 20));
  float* out = (float*)d_out;

  qkv_proj<<<128, 256, 0, stream>>>(x, wq, bq, wk, bk, wv, bv, Qb, Kb, Vt);

  const size_t need4 = (29ll << 20) + (4ll * 16384 * sizeof(float));
  if (ws_size >= need4) {
    float* Lp = (float*)(w + (29ll << 20));
    attn<4><<<512, 256, 0, stream>>>(Qb, Kb, Vt, out, O1, O2, O3, Lp);
    combine<4><<<1024, 256, 0, stream>>>(O1, O2, O3, Lp, x, gm, out);
  } else {
    float* Lp = (float*)(w + (13ll << 20));
    attn<2><<<256, 256, 0, stream>>>(Qb, Kb, Vt, out, O1, O1, O1, Lp);
    combine<2><<<1024, 256, 0, stream>>>(O1, O1, O1, Lp, x, gm, out);
  }
}

// Round 6
// 64.950 us; speedup vs baseline: 3.1530x; 1.0007x over previous
//
#include <hip/hip_runtime.h>
#include <hip/hip_bf16.h>

// SAGAN self-attention, MI355X (gfx950).
// B=4, H=W=64 (N=4096), C=128, d_qk=16. out = gamma * softmax(QK^T) V + x.
//
//  k1 qkv_proj : MFMA GEMM x[16384,128] @ [wq|wk|wv] -> Qb,Kb bf16 [4,4096,16],
//                Vt bf16 [4,128,4096] (transposed). Q pre-scaled by log2(e).
//  k2 attn     : flash attention, mfma_f32_32x32x16_bf16, swapped QK^T.
//                NO max tracking: p = exp2(s - 16) (safe: |s|log2e <~ 40 << 127,
//                softmax shift-invariant; bias folded into the QK MFMA C operand).
//                l deferred to epilogue. K global->reg (L2-resident, prefetched);
//                LDS = V only. k-split=NKS bf16 partials in ws.
//  k3 combine  : out = gamma * (sum_p O_p) / (sum_p l_p) + x.

typedef __attribute__((ext_vector_type(4)))  short short4v;
typedef __attribute__((ext_vector_type(8)))  short short8;
typedef __attribute__((ext_vector_type(16))) float f32x16;
typedef unsigned short u16;

#define LOG2E 1.4426950408889634f

__device__ __forceinline__ u16 f2bf(float f) {
  __hip_bfloat16 h = __float2bfloat16(f);
  return __builtin_bit_cast(u16, h);
}
__device__ __forceinline__ float bf2f(u16 u) {
  unsigned v = (unsigned)u << 16;
  return __builtin_bit_cast(float, v);
}
__device__ __forceinline__ unsigned pk2bf(float lo, float hi) {
  return (unsigned)f2bf(lo) | ((unsigned)f2bf(hi) << 16);
}
// cross-half (lane i <-> i+32) sum via permlane32_swap: pure VALU, no DS latency
__device__ __forceinline__ float xhalf_sum(float x) {
  float a = x, b = x;
  asm("v_permlane32_swap_b32 %0, %1" : "+v"(a), "+v"(b));
  return a + b;
}

// ---------------------------------------------------------------- kernel 1
// grid 128 = b(4) x rt(32): block computes rows [rt*128, +128) of batch b.
__global__ __launch_bounds__(256) void qkv_proj(
    const float* __restrict__ x,
    const float* __restrict__ wq, const float* __restrict__ bq,
    const float* __restrict__ wk, const float* __restrict__ bk,
    const float* __restrict__ wv, const float* __restrict__ bv,
    u16* __restrict__ Qb, u16* __restrict__ Kb, u16* __restrict__ Vt)
{
  __shared__ u16 xs[128 * 136];
  __shared__ u16 ws[160 * 136];
  const int tid = threadIdx.x;
  const int b   = blockIdx.x >> 5;
  const int n0  = (blockIdx.x & 31) * 128;

  const float4* xg = (const float4*)(x + ((size_t)b * 4096 + n0) * 128);
#pragma unroll
  for (int p = 0; p < 16; ++p) {
    int idx = tid + p * 256;              // 4096 float4s
    float4 v = xg[idx];
    int n = idx >> 5, i4 = idx & 31;
    short4v pk;
    pk[0] = (short)f2bf(v.x); pk[1] = (short)f2bf(v.y);
    pk[2] = (short)f2bf(v.z); pk[3] = (short)f2bf(v.w);
    *(short4v*)(xs + n * 136 + i4 * 4) = pk;
  }
#pragma unroll
  for (int p = 0; p < 8; ++p) {
    int idx = tid + p * 256;              // 2048 = 128x16
    int k = idx >> 4, d = idx & 15;
    ws[d * 136 + k]        = f2bf(wq[idx] * LOG2E);
    ws[(16 + d) * 136 + k] = f2bf(wk[idx]);
  }
#pragma unroll
  for (int p = 0; p < 64; ++p) {
    int idx = tid + p * 256;              // 16384 = 128x128
    int k = idx >> 7, c = idx & 127;
    ws[(32 + c) * 136 + k] = f2bf(wv[idx]);
  }
  __syncthreads();

  const int lane = tid & 63, wid = tid >> 6;
  const int ln31 = lane & 31, hi = lane >> 5;

#pragma unroll
  for (int j = 0; j < 5; ++j) {
    int t  = wid + j * 4;                 // 0..19
    int mt = t / 5, nt = t % 5;
    const u16* arow = xs + (mt * 32 + ln31) * 136 + hi * 8;
    const u16* brow = ws + (nt * 32 + ln31) * 136 + hi * 8;
    f32x16 acc = (f32x16)0.0f;
#pragma unroll
    for (int ks = 0; ks < 8; ++ks) {
      short8 a = *(const short8*)(arow + ks * 16);
      short8 w = *(const short8*)(brow + ks * 16);
      acc = __builtin_amdgcn_mfma_f32_32x32x16_bf16(a, w, acc, 0, 0, 0);
    }
    if (nt == 0) {
      float bias = (ln31 < 16) ? bq[ln31] * LOG2E : bk[ln31 & 15];
      u16* base = ((ln31 < 16) ? Qb : Kb)
                + ((size_t)b * 4096 + n0 + mt * 32) * 16 + (ln31 & 15);
#pragma unroll
      for (int r = 0; r < 16; ++r) {
        int nl = (r & 3) + 8 * (r >> 2) + 4 * hi;   // C/D row map
        base[nl * 16] = f2bf(acc[r] + bias);
      }
    } else {
      int c = (nt - 1) * 32 + ln31;
      float bias = bv[c];
      u16* vb = Vt + ((size_t)b * 128 + c) * 4096 + n0 + mt * 32 + 4 * hi;
#pragma unroll
      for (int g = 0; g < 4; ++g) {
        short4v pk;
        pk[0] = (short)f2bf(acc[g*4+0] + bias);
        pk[1] = (short)f2bf(acc[g*4+1] + bias);
        pk[2] = (short)f2bf(acc[g*4+2] + bias);
        pk[3] = (short)f2bf(acc[g*4+3] + bias);
        *(short4v*)(vb + 8 * g) = pk;
      }
    }
  }
}

// ---------------------------------------------------------------- kernel 2
// grid 4*32*NKS. block 256 = 4 waves, wave owns 32 q-rows (128 q/block).
// Block handles k range [ks*4096/NKS, +4096/NKS) in 64-k chunks.
// Partials: Ob bf16 [NKS][4][4096][128], Lp f32 [NKS][16384].
template<int NKS>
__global__ __launch_bounds__(256) void attn(
    const u16* __restrict__ Qb, const u16* __restrict__ Kb,
    const u16* __restrict__ Vt,
    u16* __restrict__ Ob, float* __restrict__ Lp)
{
  // per buffer: V 128 rows x 144B (64 k bf16 + 16B pad) = 18432
  __shared__ __align__(16) char sm[2][18432];
  const int tid  = threadIdx.x;
  const int lane = tid & 63;
  const int wid  = tid >> 6;
  const int ln31 = lane & 31;
  const int hi   = lane >> 5;

  constexpr int KSH    = (NKS == 8) ? 3 : (NKS == 4) ? 2 : 1;
  constexpr int CHUNKS = 64 / NKS;        // 64-k chunks per block
  const int b   = blockIdx.x >> (5 + KSH);
  const int qt  = (blockIdx.x >> KSH) & 31;
  const int ks  = blockIdx.x & (NKS - 1);
  const int qw  = qt * 128 + wid * 32;    // wave's first q row (within batch)
  const int kb0 = ks * (4096 / NKS);

  // Q B-fragment: col q = ln31, d = hi*8 + j (Q pre-scaled by log2e)
  const short8 qf = *(const short8*)(Qb + (((size_t)b * 4096 + qw + ln31) << 4) + (hi << 3));

  f32x16 acc[4];
#pragma unroll
  for (int ct = 0; ct < 4; ++ct) acc[ct] = (f32x16)0.0f;
  float lacc = 0.f;
  const f32x16 cbias = (f32x16)(-16.0f);  // s = q.k*log2e - 16, free in MFMA C

  const char* vg = (const char*)(Vt + (size_t)b * 128 * 4096);
  const char* kg = (const char*)(Kb + (size_t)b * 4096 * 16);
  const int vc = tid >> 1;                // V channel row this thread stages
  const int vp = tid & 1;                 // which 64B half of the 128B row

  uint4 rv0, rv1, rv2, rv3;               // V staging regs (T14 split)
  uint4 rkc0, rkc1, rkn0, rkn1;           // K fragments: current / next chunk

  auto loadV = [&](int kb) {              // global -> regs (issued early)
    const char* vs = vg + (size_t)vc * 8192 + (size_t)kb * 2 + vp * 64;
    rv0 = *(const uint4*)(vs);
    rv1 = *(const uint4*)(vs + 16);
    rv2 = *(const uint4*)(vs + 32);
    rv3 = *(const uint4*)(vs + 48);
  };
  auto loadK = [&](int kb, uint4& k0, uint4& k1) {  // direct to regs, coalesced
    const char* kr = kg + (size_t)(kb + ln31) * 32 + hi * 16;
    k0 = *(const uint4*)(kr);             // kt=0 rows
    k1 = *(const uint4*)(kr + 1024);      // kt=1 rows (+32 rows * 32B)
  };
  auto storeV = [&](char* buf) {          // regs -> LDS (after compute)
    char* vd = buf + vc * 144 + vp * 64;
    *(uint4*)(vd)      = rv0;
    *(uint4*)(vd + 16) = rv1;
    *(uint4*)(vd + 32) = rv2;
    *(uint4*)(vd + 48) = rv3;
  };

  auto compute = [&](const char* buf, uint4 k0, uint4 k1) {
#pragma unroll
    for (int kt = 0; kt < 2; ++kt) {      // two independent 32-k subtiles
      // swapped QK^T: A = K rows (kk = ln31), B = Q -> D[kk][q], lane col = q
      short8 kf = __builtin_bit_cast(short8, kt ? k1 : k0);
      f32x16 s = __builtin_amdgcn_mfma_f32_32x32x16_bf16(kf, qf, cbias, 0, 0, 0);

      // p = exp2(s) directly; s[r] is kk = (r&3)+8*(r>>2)+4*hi
      float p[16];
#pragma unroll
      for (int r = 0; r < 16; ++r) p[r] = exp2f(s[r]);
      // tree sum (depth 4), deferred cross-half to epilogue
      float a0 = p[0]+p[1],  a1 = p[2]+p[3],  a2 = p[4]+p[5],  a3 = p[6]+p[7];
      float b0 = p[8]+p[9],  b1 = p[10]+p[11], b2 = p[12]+p[13], b3 = p[14]+p[15];
      lacc += ((a0+a1)+(a2+a3)) + ((b0+b1)+(b2+b3));

      // P -> bf16 PV A-fragments: packed pairs + permlane32_swap (T12)
      unsigned u0 = pk2bf(p[0], p[1]),  u1 = pk2bf(p[2], p[3]);
      unsigned u2 = pk2bf(p[4], p[5]),  u3 = pk2bf(p[6], p[7]);
      asm("v_permlane32_swap_b32 %0, %1" : "+v"(u0), "+v"(u2));
      asm("v_permlane32_swap_b32 %0, %1" : "+v"(u1), "+v"(u3));
      unsigned y0 = pk2bf(p[8], p[9]),   y1 = pk2bf(p[10], p[11]);
      unsigned y2 = pk2bf(p[12], p[13]), y3 = pk2bf(p[14], p[15]);
      asm("v_permlane32_swap_b32 %0, %1" : "+v"(y0), "+v"(y2));
      asm("v_permlane32_swap_b32 %0, %1" : "+v"(y1), "+v"(y3));
      union { unsigned u[4]; short8 s8; } pa0, pa1;
      pa0.u[0] = u0; pa0.u[1] = u1; pa0.u[2] = u2; pa0.u[3] = u3;
      pa1.u[0] = y0; pa1.u[1] = y1; pa1.u[2] = y2; pa1.u[3] = y3;

      // PV: acc[ct] += P[32q x 32k] @ V[32k x 32c] (two K=16 MFMAs per ct)
      __builtin_amdgcn_s_setprio(1);
#pragma unroll
      for (int ct = 0; ct < 4; ++ct) {
        const char* vrow = buf + (ct * 32 + ln31) * 144 + kt * 64 + hi * 16;
        short8 vf0 = *(const short8*)(vrow);        // k 0..15 of subtile
        short8 vf1 = *(const short8*)(vrow + 32);   // k 16..31
        acc[ct] = __builtin_amdgcn_mfma_f32_32x32x16_bf16(pa0.s8, vf0, acc[ct], 0, 0, 0);
        acc[ct] = __builtin_amdgcn_mfma_f32_32x32x16_bf16(pa1.s8, vf1, acc[ct], 0, 0, 0);
      }
      __builtin_amdgcn_s_setprio(0);
    }
  };

  loadV(kb0);
  loadK(kb0, rkc0, rkc1);
  storeV(sm[0]);
  __syncthreads();
#pragma unroll 1
  for (int it = 0; it < CHUNKS; ++it) {
    if (it < CHUNKS - 1) {                // prefetch next chunk (V + K) early
      loadV(kb0 + (it + 1) * 64);
      loadK(kb0 + (it + 1) * 64, rkn0, rkn1);
    }
    compute(sm[it & 1], rkc0, rkc1);
    if (it < CHUNKS - 1) storeV(sm[(it + 1) & 1]);
    __syncthreads();                      // single barrier per iter (dbuf)
    rkc0 = rkn0; rkc1 = rkn1;
  }

  // epilogue: cross-half l reduce, store bf16 partial O and l
  float lt = xhalf_sum(lacc);
  if (lane < 32)
    Lp[(size_t)ks * 16384 + (size_t)b * 4096 + qw + lane] = lt;
  u16* Op = Ob + ((size_t)ks * 16384 + (size_t)b * 4096 + qw) * 128;
#pragma unroll
  for (int ct = 0; ct < 4; ++ct) {
#pragma unroll
    for (int r = 0; r < 16; ++r) {
      int q = (r & 3) + 8 * (r >> 2) + 4 * hi;     // C/D row map (m74/m101)
      Op[(size_t)q * 128 + ct * 32 + ln31] = f2bf(acc[ct][r]);
    }
  }
}

// ---------------------------------------------------------------- kernel 3
template<int NKS>
__global__ __launch_bounds__(256) void combine(
    const u16* __restrict__ Ob, const float* __restrict__ Lp,
    const float* __restrict__ x, const float* __restrict__ gamma,
    float* __restrict__ out)
{
  int i    = blockIdx.x * 256 + threadIdx.x;   // 0..262143
  int nrow = i >> 4;
  int c0   = (i & 15) << 3;

  float wsum = 0.f;
#pragma unroll
  for (int p = 0; p < NKS; ++p) wsum += Lp[(size_t)p * 16384 + nrow];
  float inv = gamma[0] / wsum;

  size_t off = (size_t)nrow * 128 + c0;
  float accv[8];
#pragma unroll
  for (int j = 0; j < 8; ++j) accv[j] = 0.f;
#pragma unroll
  for (int p = 0; p < NKS; ++p) {
    short8 v = *(const short8*)(Ob + (size_t)p * 16384 * 128 + off);
#pragma unroll
    for (int j = 0; j < 8; ++j) accv[j] += bf2f((u16)v[j]);
  }
  float4 xa = *(const float4*)(x + off);
  float4 xb = *(const float4*)(x + off + 4);
  float4 ra, rb;
  ra.x = fmaf(accv[0], inv, xa.x); ra.y = fmaf(accv[1], inv, xa.y);
  ra.z = fmaf(accv[2], inv, xa.z); ra.w = fmaf(accv[3], inv, xa.w);
  rb.x = fmaf(accv[4], inv, xb.x); rb.y = fmaf(accv[5], inv, xb.y);
  rb.z = fmaf(accv[6], inv, xb.z); rb.w = fmaf(accv[7], inv, xb.w);
  *(float4*)(out + off)     = ra;
  *(float4*)(out + off + 4) = rb;
}

// ---------------------------------------------------------------- launch
extern "C" void kernel_launch(void* const* d_in, const int* in_sizes, int n_in,
                              void* d_out, int out_size, void* d_ws, size_t ws_size,
                              hipStream_t stream)
{
  const float* x  = (const float*)d_in[0];
  const float* wq = (const float*)d_in[1];
  const float* bq = (const float*)d_in[2];
  const float* wk = (const float*)d_in[3];
  const float* bk = (const float*)d_in[4];
  const float* wv = (const float*)d_in[5];
  const float* bv = (const float*)d_in[6];
  const float* gm = (const float*)d_in[7];

  // ws layout:
  //  [0, 512K)    Qb bf16 [4][4096][16]   (pre-scaled by log2e)
  //  [512K, 1M)   Kb bf16 [4][4096][16]
  //  [1M, 5M)     Vt bf16 [4][128][4096]
  //  [5M, ...)    Ob bf16 [NKS][4][4096][128]  (4 MB per split)
  //  after Ob:    Lp f32  [NKS][16384]
  char* w = (char*)d_ws;
  u16*   Qb = (u16*)(w);
  u16*   Kb = (u16*)(w + (512ll << 10));
  u16*   Vt = (u16*)(w + (1ll << 20));
  u16*   Ob = (u16*)(w + (5ll << 20));
  float* out = (float*)d_out;

  qkv_proj<<<128, 256, 0, stream>>>(x, wq, bq, wk, bk, wv, bv, Qb, Kb, Vt);

  const size_t need8 = (5ll << 20) + 8ll * (4ll << 20) + 8ll * 16384 * 4;
  if (ws_size >= need8) {
    float* Lp = (float*)(w + (5ll << 20) + 8ll * (4ll << 20));
    attn<8><<<1024, 256, 0, stream>>>(Qb, Kb, Vt, Ob, Lp);
    combine<8><<<1024, 256, 0, stream>>>(Ob, Lp, x, gm, out);
  } else {
    float* Lp = (float*)(w + (5ll << 20) + 4ll * (4ll << 20));
    attn<4><<<512, 256, 0, stream>>>(Qb, Kb, Vt, Ob, Lp);
    combine<4><<<1024, 256, 0, stream>>>(Ob, Lp, x, gm, out);
  }
}